// Round 10
// baseline (619.405 us; speedup 1.0000x reference)
//
#include <hip/hip_runtime.h>

// GCN 2-layer collapsed (x is [N,1] => layer 1 is rank-1):
//   out[c] = dis[c]*(sum_{r->c} gp[r] + gp[c]) + b2,  gp[r] = (relu(W1*a[r]+b1)@W2)*dis[r]
//   a[r]   = dis[r]*(sum_{r'->r} p[r'] + p[r]),       p[r']=x[r']*dis[r'], dis=1/sqrt(deg+1)
//
// Hard-won rules: (1) global atomics 20G/s wall; (2) scattered 4B global stores ~38B
// write-through each -> only run-coalesced writes; (3) random gathers are REQUEST-rate
// walled (~90G/s) even on cache hits -> LDS-ize via coalesced preload; (4) preload
// aggregation is occupancy-bound: 32KB LDS fast (R9 s2), 64KB slow (R9 o2 = 242us @21%).
// R10: 2048-node col/row chunks (CC=RC=245). s2 = 16KB (8 blk/CU), o2 = 32KB (5 blk/CU),
// sortB keys = row>>11 (245 keys, key recomputed from packed word, runs ~33 = 132B).

#define KMAX 512
#define PTPB  512
#define PU    16
#define PTILE (PTPB * PU)

#define CSH2  11
#define CN2   2048
#define HSL   8        // hist slices per chunk
#define SSL   8        // sort/agg slices per chunk
#define RCB   256      // max row-chunks (n <= 2^19)

#define ATPB  256      // path1 aggregation block

// ---------- zero ----------
__global__ void k_zero(int* __restrict__ a, int m) {
    int i = blockIdx.x * blockDim.x + threadIdx.x;
    if (i < m) a[i] = 0;
}

// ---------- coarse histogram ----------
template<int S>
__global__ void k_count(const int* __restrict__ col, int ne, int ne4,
                        int* __restrict__ totals, int K) {
    __shared__ int cnt[KMAX];
    for (int i = threadIdx.x; i < K; i += blockDim.x) cnt[i] = 0;
    __syncthreads();
    int tid = blockIdx.x * blockDim.x + threadIdx.x;
    int stride = gridDim.x * blockDim.x;
    const int4* col4 = (const int4*)col;
    for (int e = tid; e < ne4; e += stride) {
        int4 cc = col4[e];
        atomicAdd(&cnt[cc.x >> S], 1);
        atomicAdd(&cnt[cc.y >> S], 1);
        atomicAdd(&cnt[cc.z >> S], 1);
        atomicAdd(&cnt[cc.w >> S], 1);
    }
    for (int e = (ne4 << 2) + tid; e < ne; e += stride)
        atomicAdd(&cnt[col[e] >> S], 1);
    __syncthreads();
    for (int i = threadIdx.x; i < K; i += blockDim.x)
        if (cnt[i]) atomicAdd(&totals[i], cnt[i]);
}

// ---------- serial scan (K<=512) ----------
__global__ void k_scan(const int* __restrict__ totals, int* __restrict__ bbase,
                       int* __restrict__ cursor, int K) {
    if (threadIdx.x == 0 && blockIdx.x == 0) {
        int run = 0;
        for (int k = 0; k < K; ++k) { bbase[k] = run; cursor[k] = run; run += totals[k]; }
        bbase[K] = run;
    }
}

// ---------- tile-local LDS counting sort partition (key = col>>S) ----------
template<int S>
__global__ __launch_bounds__(PTPB) void k_part(
    const int* __restrict__ row, const int* __restrict__ col, int ne,
    int* __restrict__ cursor, int* __restrict__ packed, int K)
{
    constexpr int CNL = 1 << S;
    __shared__ int s_cnt[KMAX];
    __shared__ int s_start[KMAX + 1];
    __shared__ int s_cur[KMAX];
    __shared__ int s_gbase[KMAX];
    __shared__ int s_sorted[PTILE];

    int tb = blockIdx.x * PTILE;
    int tilecount = ne - tb;
    if (tilecount > PTILE) tilecount = PTILE;

    for (int i = threadIdx.x; i < K; i += PTPB) s_cnt[i] = 0;
    __syncthreads();

    int r[PU], c[PU];
    const int4* row4 = (const int4*)row;
    const int4* col4 = (const int4*)col;
    int tb4 = tb >> 2;
#pragma unroll
    for (int j = 0; j < PU / 4; ++j) {
        int g4 = tb4 + j * PTPB + threadIdx.x;
        int e = g4 << 2;
        if (e + 3 < ne) {
            int4 rr = row4[g4];
            int4 cc = col4[g4];
            r[4 * j + 0] = rr.x; r[4 * j + 1] = rr.y; r[4 * j + 2] = rr.z; r[4 * j + 3] = rr.w;
            c[4 * j + 0] = cc.x; c[4 * j + 1] = cc.y; c[4 * j + 2] = cc.z; c[4 * j + 3] = cc.w;
        } else {
#pragma unroll
            for (int q = 0; q < 4; ++q) {
                int e2 = e + q;
                if (e2 < ne) { r[4 * j + q] = row[e2]; c[4 * j + q] = col[e2]; }
                else { r[4 * j + q] = 0; c[4 * j + q] = -1; }
            }
        }
    }
#pragma unroll
    for (int j = 0; j < PU; ++j)
        if (c[j] >= 0) atomicAdd(&s_cnt[c[j] >> S], 1);
    __syncthreads();

    if (threadIdx.x == 0) {
        int run = 0;
        for (int k = 0; k < K; ++k) { s_start[k] = run; run += s_cnt[k]; }
        s_start[K] = run;
    }
    __syncthreads();
    if ((int)threadIdx.x < K) {
        int n0 = s_cnt[threadIdx.x];
        s_gbase[threadIdx.x] = n0 ? atomicAdd(&cursor[threadIdx.x], n0) : 0;
        s_cur[threadIdx.x] = s_start[threadIdx.x];
    }
    __syncthreads();

#pragma unroll
    for (int j = 0; j < PU; ++j) {
        if (c[j] >= 0) {
            int ck = c[j] >> S;
            int pos = atomicAdd(&s_cur[ck], 1);
            s_sorted[pos] = (r[j] << S) | (c[j] & (CNL - 1));
        }
    }
    __syncthreads();

    for (int i = threadIdx.x; i < tilecount; i += PTPB) {
        int v = s_sorted[i];
        int lo = 0, hi = K;
        while (hi - lo > 1) {
            int mid = (lo + hi) >> 1;
            if (s_start[mid] <= i) lo = mid; else hi = mid;
        }
        packed[s_gbase[lo] + (i - s_start[lo])] = v;
    }
}

// ---------- R10: fused node-degree + row-chunk histogram on packedA ----------
__global__ __launch_bounds__(256) void k_histAB(
    const int* __restrict__ packedA, const int* __restrict__ cbase,
    unsigned short* __restrict__ pcnt, int* __restrict__ rowh, int n)
{
    __shared__ int cnt[CN2];     // 8 KB
    __shared__ int rcnt[RCB];    // 1 KB
    int k = blockIdx.x / HSL, sl = blockIdx.x % HSL;
    int node0 = k << CSH2;
    int nn = min(CN2, n - node0);
    for (int i = threadIdx.x; i < CN2; i += 256) cnt[i] = 0;
    if ((int)threadIdx.x < RCB) rcnt[threadIdx.x] = 0;
    __syncthreads();
    int e0 = cbase[k], e1 = cbase[k + 1];
    long long len = e1 - e0;
    int es = e0 + (int)((len * sl) / HSL);
    int ee = e0 + (int)((len * (sl + 1)) / HSL);
    for (int e = es + (int)threadIdx.x; e < ee; e += 256) {
        int v = packedA[e];
        atomicAdd(&cnt[v & (CN2 - 1)], 1);
        atomicAdd(&rcnt[((unsigned)v) >> 22], 1);   // row>>11
    }
    __syncthreads();
    unsigned short* dst = pcnt + (size_t)sl * n + node0;
    for (int i = threadIdx.x; i < nn; i += 256) dst[i] = (unsigned short)cnt[i];
    if ((int)threadIdx.x < RCB)
        rowh[((size_t)k * HSL + sl) * RCB + threadIdx.x] = rcnt[threadIdx.x];
}

// ---------- R10: reduce degree -> dis, p ----------
__global__ void r_disp(const float* __restrict__ x, const unsigned short* __restrict__ pcnt,
                       float* __restrict__ dis, float* __restrict__ p, int n)
{
    int i = blockIdx.x * blockDim.x + threadIdx.x;
    if (i >= n) return;
    int d = 1;
#pragma unroll
    for (int s = 0; s < HSL; ++s) d += pcnt[(size_t)s * n + i];
    float ds = rsqrtf((float)d);
    dis[i] = ds;
    p[i] = x[i] * ds;
}

// ---------- R10: per-chunk scan of row-chunk hist -> segBase, cursorB ----------
__global__ void k_scanB(const int* __restrict__ rowh, const int* __restrict__ cbase,
                        int* __restrict__ segBase, int* __restrict__ cursorB,
                        int RC, int RC1)
{
    int k = blockIdx.x;
    if (threadIdx.x != 0) return;
    int run = cbase[k];
    const int* rh = rowh + (size_t)k * HSL * RCB;
    for (int rc = 0; rc < RC; ++rc) {
        int tot = 0;
        for (int s = 0; s < HSL; ++s) tot += rh[s * RCB + rc];
        segBase[(size_t)k * RC1 + rc] = run;
        cursorB[(size_t)k * RC1 + rc] = run;
        run += tot;
    }
    segBase[(size_t)k * RC1 + RC] = cbase[k + 1];
}

// ---------- R10: stage-B sort by row-chunk (<=256 keys, key recomputed) ----------
__global__ __launch_bounds__(256) void k_sortB(
    const int* __restrict__ packedA, const int* __restrict__ cbase,
    int* __restrict__ cursorB, int* __restrict__ packedB, int RC1)
{
    __shared__ int s_cnt[RCB];
    __shared__ int s_start[RCB + 1];
    __shared__ int s_cur[RCB];
    __shared__ int s_gbase[RCB];
    __shared__ int s_sorted[8192];   // 32 KB

    int k = blockIdx.x / SSL, sl = blockIdx.x % SSL;
    int e0 = cbase[k], e1 = cbase[k + 1];
    long long len = e1 - e0;
    int es = e0 + (int)((len * sl) / SSL);
    int ee = e0 + (int)((len * (sl + 1)) / SSL);

    for (int t0 = es; t0 < ee; t0 += 8192) {
        int tc = min(8192, ee - t0);
        if ((int)threadIdx.x < RCB) s_cnt[threadIdx.x] = 0;
        __syncthreads();
        int v[32];
#pragma unroll
        for (int j = 0; j < 32; ++j) {
            int idx = t0 + j * 256 + (int)threadIdx.x;
            v[j] = (idx < ee && (idx - t0) < 8192) ? packedA[idx] : -1;
            if (v[j] >= 0) atomicAdd(&s_cnt[((unsigned)v[j]) >> 22], 1);
        }
        __syncthreads();
        if (threadIdx.x == 0) {
            int run = 0;
            for (int q = 0; q < RCB; ++q) { s_start[q] = run; run += s_cnt[q]; }
            s_start[RCB] = run;
        }
        __syncthreads();
        if ((int)threadIdx.x < RCB) {
            int c0 = s_cnt[threadIdx.x];
            s_gbase[threadIdx.x] = c0 ?
                atomicAdd(&cursorB[(size_t)k * RC1 + (int)threadIdx.x], c0) : 0;
            s_cur[threadIdx.x] = s_start[threadIdx.x];
        }
        __syncthreads();
#pragma unroll
        for (int j = 0; j < 32; ++j) {
            if (v[j] >= 0) {
                int pos = atomicAdd(&s_cur[((unsigned)v[j]) >> 22], 1);
                s_sorted[pos] = v[j];
            }
        }
        __syncthreads();
        for (int i = threadIdx.x; i < tc; i += 256) {
            int val = s_sorted[i];
            int key = ((unsigned)val) >> 22;
            packedB[s_gbase[key] + (i - s_start[key])] = val;
        }
        __syncthreads();
    }
}

// ---------- R10: scalar aggregation with LDS-preloaded p row-chunks (16 KB) ----------
__global__ __launch_bounds__(256) void k_s2(
    const int* __restrict__ packedB, const int* __restrict__ segBase,
    const float* __restrict__ p, float* __restrict__ ps, int n, int RC, int RC1)
{
    __shared__ float sv[CN2];   // 8 KB
    __shared__ float pl[CN2];   // 8 KB
    int k = blockIdx.x / SSL, sl = blockIdx.x % SSL;
    int node0 = k << CSH2;
    int nn = min(CN2, n - node0);
    for (int i = threadIdx.x; i < CN2; i += 256) sv[i] = 0.0f;
    int rc0 = (RC * sl) / SSL, rc1 = (RC * (sl + 1)) / SSL;
    const int* sb = segBase + (size_t)k * RC1;
    for (int rc = rc0; rc < rc1; ++rc) {
        int e0 = sb[rc], e1 = sb[rc + 1];
        if (e0 == e1) continue;              // block-uniform
        __syncthreads();
        int r0 = rc << CSH2;
        int rn = min(CN2, n - r0);
        for (int i = threadIdx.x; i < rn; i += 256) pl[i] = p[r0 + i];
        __syncthreads();
        for (int e = e0 + (int)threadIdx.x; e < e1; e += 256) {
            int v = packedB[e];
            atomicAdd(&sv[v & (CN2 - 1)], pl[(v >> CSH2) & (CN2 - 1)]);
        }
    }
    __syncthreads();
    float* dst = ps + (size_t)sl * n + node0;
    for (int i = threadIdx.x; i < nn; i += 256) dst[i] = sv[i];
}

// ---------- R10: reduce s + fused MLP -> gp ----------
__global__ void r_gp8(const float* __restrict__ ps, const float* __restrict__ p,
                      const float* __restrict__ dis,
                      const float* __restrict__ W1, const float* __restrict__ b1,
                      const float* __restrict__ W2, float* __restrict__ gp, int n)
{
    int i = blockIdx.x * blockDim.x + threadIdx.x;
    if (i >= n) return;
    float sum = p[i];
#pragma unroll
    for (int s = 0; s < SSL; ++s) sum += ps[(size_t)s * n + i];
    float d = dis[i];
    float a = d * sum;
    float g0 = 0.0f, g1 = 0.0f;
#pragma unroll
    for (int q = 0; q < 16; ++q) {
        float h = fmaxf(W1[q] * a + b1[q], 0.0f);
        g0 += h * W2[2 * q];
        g1 += h * W2[2 * q + 1];
    }
    ((float2*)gp)[i] = make_float2(g0 * d, g1 * d);
}

// ---------- R10: float2 aggregation with LDS-preloaded gp row-chunks (32 KB) ----------
__global__ __launch_bounds__(256) void k_o2(
    const int* __restrict__ packedB, const int* __restrict__ segBase,
    const float* __restrict__ gp, float* __restrict__ pout, int n, int RC, int RC1)
{
    __shared__ float ox[CN2];     // 8 KB
    __shared__ float oy[CN2];     // 8 KB
    __shared__ float2 pl2[CN2];   // 16 KB
    int k = blockIdx.x / SSL, sl = blockIdx.x % SSL;
    int node0 = k << CSH2;
    int nn = min(CN2, n - node0);
    for (int i = threadIdx.x; i < CN2; i += 256) { ox[i] = 0.0f; oy[i] = 0.0f; }
    int rc0 = (RC * sl) / SSL, rc1 = (RC * (sl + 1)) / SSL;
    const int* sb = segBase + (size_t)k * RC1;
    const float2* gp2 = (const float2*)gp;
    for (int rc = rc0; rc < rc1; ++rc) {
        int e0 = sb[rc], e1 = sb[rc + 1];
        if (e0 == e1) continue;
        __syncthreads();
        int r0 = rc << CSH2;
        int rn = min(CN2, n - r0);
        for (int i = threadIdx.x; i < rn; i += 256) pl2[i] = gp2[r0 + i];
        __syncthreads();
        for (int e = e0 + (int)threadIdx.x; e < e1; e += 256) {
            int v = packedB[e];
            float2 g = pl2[(v >> CSH2) & (CN2 - 1)];
            int c = v & (CN2 - 1);
            atomicAdd(&ox[c], g.x);
            atomicAdd(&oy[c], g.y);
        }
    }
    __syncthreads();
    float2* dst = (float2*)pout + (size_t)sl * n + node0;
    for (int i = threadIdx.x; i < nn; i += 256) dst[i] = make_float2(ox[i], oy[i]);
}

// ---------- R10: reduce -> out ----------
__global__ void r_out8(const float* __restrict__ pout, const float* __restrict__ gp,
                       const float* __restrict__ dis, const float* __restrict__ b2,
                       float* __restrict__ out, int n)
{
    int i = blockIdx.x * blockDim.x + threadIdx.x;
    if (i >= n) return;
    const float2* po2 = (const float2*)pout;
    float2 g = ((const float2*)gp)[i];
    float sx = g.x, sy = g.y;
#pragma unroll
    for (int s = 0; s < SSL; ++s) {
        float2 t = po2[(size_t)s * n + i];
        sx += t.x; sy += t.y;
    }
    float d = dis[i];
    ((float2*)out)[i] = make_float2(d * sx + b2[0], d * sy + b2[1]);
}

// ---------- path1 (R5) kernels ----------
template<int S>
__device__ inline void slice_bounds(const int* bbase, int k, int s, int& es, int& ee) {
    int e0 = bbase[k], e1 = bbase[k + 1];
    long long len = e1 - e0;
    es = e0 + (int)((len * s) / S);
    ee = e0 + (int)((len * (s + 1)) / S);
}

template<int S2, int S>
__global__ __launch_bounds__(ATPB) void k_deg_split(
    const int* __restrict__ packed, const int* __restrict__ bbase,
    int* __restrict__ pcnt, int n)
{
    constexpr int CNL = 1 << S2;
    __shared__ int cnt[CNL];
    int k = blockIdx.x / S, s = blockIdx.x % S;
    int node0 = k << S2;
    int nn = min(CNL, n - node0);
    for (int i = threadIdx.x; i < nn; i += ATPB) cnt[i] = 0;
    __syncthreads();
    int es, ee;
    slice_bounds<S>(bbase, k, s, es, ee);
    for (int e = es + (int)threadIdx.x; e < ee; e += ATPB)
        atomicAdd(&cnt[packed[e] & (CNL - 1)], 1);
    __syncthreads();
    int* dst = pcnt + (size_t)s * n + node0;
    for (int i = threadIdx.x; i < nn; i += ATPB) dst[i] = cnt[i];
}

template<int S>
__global__ void r_dis_p(const float* __restrict__ x, const int* __restrict__ pcnt,
                        float* __restrict__ dis, float* __restrict__ p, int n)
{
    int i = blockIdx.x * blockDim.x + threadIdx.x;
    if (i >= n) return;
    int d = 1;
#pragma unroll
    for (int s = 0; s < S; ++s) d += pcnt[(size_t)s * n + i];
    float ds = rsqrtf((float)d);
    dis[i] = ds;
    p[i] = x[i] * ds;
}

template<int S2, int S>
__global__ __launch_bounds__(ATPB) void k_s_split(
    const int* __restrict__ packed, const int* __restrict__ bbase,
    const float* __restrict__ p, float* __restrict__ ps, int n)
{
    constexpr int CNL = 1 << S2;
    __shared__ float sv[CNL];
    int k = blockIdx.x / S, s = blockIdx.x % S;
    int node0 = k << S2;
    int nn = min(CNL, n - node0);
    for (int i = threadIdx.x; i < nn; i += ATPB) sv[i] = 0.0f;
    __syncthreads();
    int es, ee;
    slice_bounds<S>(bbase, k, s, es, ee);
    for (int e = es + (int)threadIdx.x; e < ee; e += ATPB) {
        int v = packed[e];
        atomicAdd(&sv[v & (CNL - 1)], p[((unsigned)v) >> S2]);
    }
    __syncthreads();
    float* dst = ps + (size_t)s * n + node0;
    for (int i = threadIdx.x; i < nn; i += ATPB) dst[i] = sv[i];
}

template<int S>
__global__ void r_gp(const float* __restrict__ ps, const float* __restrict__ p,
                     const float* __restrict__ dis,
                     const float* __restrict__ W1, const float* __restrict__ b1,
                     const float* __restrict__ W2, float* __restrict__ gp, int n)
{
    int i = blockIdx.x * blockDim.x + threadIdx.x;
    if (i >= n) return;
    float sum = p[i];
#pragma unroll
    for (int s = 0; s < S; ++s) sum += ps[(size_t)s * n + i];
    float d = dis[i];
    float a = d * sum;
    float g0 = 0.0f, g1 = 0.0f;
#pragma unroll
    for (int q = 0; q < 16; ++q) {
        float h = fmaxf(W1[q] * a + b1[q], 0.0f);
        g0 += h * W2[2 * q];
        g1 += h * W2[2 * q + 1];
    }
    ((float2*)gp)[i] = make_float2(g0 * d, g1 * d);
}

template<int S2, int S>
__global__ __launch_bounds__(ATPB) void k_o_split(
    const int* __restrict__ packed, const int* __restrict__ bbase,
    const float* __restrict__ gp, float* __restrict__ pout, int n)
{
    constexpr int CNL = 1 << S2;
    __shared__ float ox[CNL];
    __shared__ float oy[CNL];
    int k = blockIdx.x / S, s = blockIdx.x % S;
    int node0 = k << S2;
    int nn = min(CNL, n - node0);
    for (int i = threadIdx.x; i < nn; i += ATPB) { ox[i] = 0.0f; oy[i] = 0.0f; }
    __syncthreads();
    int es, ee;
    slice_bounds<S>(bbase, k, s, es, ee);
    const float2* gp2 = (const float2*)gp;
    for (int e = es + (int)threadIdx.x; e < ee; e += ATPB) {
        int v = packed[e];
        float2 g = gp2[((unsigned)v) >> S2];
        atomicAdd(&ox[v & (CNL - 1)], g.x);
        atomicAdd(&oy[v & (CNL - 1)], g.y);
    }
    __syncthreads();
    float2* dst = (float2*)pout + (size_t)s * n + node0;
    for (int i = threadIdx.x; i < nn; i += ATPB) dst[i] = make_float2(ox[i], oy[i]);
}

template<int S>
__global__ void r_out(const float* __restrict__ pout, const float* __restrict__ gp,
                      const float* __restrict__ dis, const float* __restrict__ b2,
                      float* __restrict__ out, int n)
{
    int i = blockIdx.x * blockDim.x + threadIdx.x;
    if (i >= n) return;
    const float2* po2 = (const float2*)pout;
    float2 g = ((const float2*)gp)[i];
    float sx = g.x, sy = g.y;
#pragma unroll
    for (int s = 0; s < S; ++s) {
        float2 t = po2[(size_t)s * n + i];
        sx += t.x; sy += t.y;
    }
    float d = dis[i];
    ((float2*)out)[i] = make_float2(d * sx + b2[0], d * sy + b2[1]);
}

// ---------- R1 fallback ----------
__global__ void f_init_deg(float* __restrict__ deg, int n) {
    int i = blockIdx.x * blockDim.x + threadIdx.x;
    if (i < n) deg[i] = 1.0f;
}
__global__ void f_deg(const int* __restrict__ col, float* __restrict__ deg, int ne) {
    int tid = blockIdx.x * blockDim.x + threadIdx.x;
    int stride = gridDim.x * blockDim.x;
    for (int e = tid; e < ne; e += stride) atomicAdd(&deg[col[e]], 1.0f);
}
__global__ void f_dis(const float* __restrict__ x, float* __restrict__ deg_dis,
                      float* __restrict__ p, float* __restrict__ s, int n) {
    int i = blockIdx.x * blockDim.x + threadIdx.x;
    if (i >= n) return;
    float dis = rsqrtf(deg_dis[i]);
    deg_dis[i] = dis;
    float pv = x[i] * dis;
    p[i] = pv;
    s[i] = pv;
}
__global__ void f_scatter1(const int* __restrict__ row, const int* __restrict__ col,
                           const float* __restrict__ p, float* __restrict__ s, int ne) {
    int tid = blockIdx.x * blockDim.x + threadIdx.x;
    int stride = gridDim.x * blockDim.x;
    for (int e = tid; e < ne; e += stride) atomicAdd(&s[col[e]], p[row[e]]);
}
__global__ void f_node(const float* __restrict__ dis, const float* __restrict__ s,
                       const float* __restrict__ W1, const float* __restrict__ b1,
                       const float* __restrict__ W2,
                       float* __restrict__ gp, float* __restrict__ out, int n) {
    int i = blockIdx.x * blockDim.x + threadIdx.x;
    if (i >= n) return;
    float d = dis[i];
    float a = d * s[i];
    float g0 = 0.0f, g1 = 0.0f;
#pragma unroll
    for (int q = 0; q < 16; ++q) {
        float h = fmaxf(W1[q] * a + b1[q], 0.0f);
        g0 += h * W2[2 * q];
        g1 += h * W2[2 * q + 1];
    }
    ((float2*)gp)[i] = make_float2(g0 * d, g1 * d);
    ((float2*)out)[i] = make_float2(g0 * d, g1 * d);
}
__global__ void f_scatter2(const int* __restrict__ row, const int* __restrict__ col,
                           const float* __restrict__ gp, float* __restrict__ out, int ne) {
    int tid = blockIdx.x * blockDim.x + threadIdx.x;
    int stride = gridDim.x * blockDim.x;
    const float2* gp2 = (const float2*)gp;
    for (int e = tid; e < ne; e += stride) {
        float2 g = gp2[row[e]];
        atomicAdd(&out[2 * col[e]], g.x);
        atomicAdd(&out[2 * col[e] + 1], g.y);
    }
}
__global__ void f_final(const float* __restrict__ dis, const float* __restrict__ b2,
                        float* __restrict__ out, int n) {
    int i = blockIdx.x * blockDim.x + threadIdx.x;
    if (i >= n) return;
    float d = dis[i];
    float2* out2 = (float2*)out;
    float2 t = out2[i];
    out2[i] = make_float2(d * t.x + b2[0], d * t.y + b2[1]);
}

// ---------------- launch ----------------

extern "C" void kernel_launch(void* const* d_in, const int* in_sizes, int n_in,
                              void* d_out, int out_size, void* d_ws, size_t ws_size,
                              hipStream_t stream) {
    const float* x = (const float*)d_in[0];
    const int* edge_index = (const int*)d_in[1];
    const float* W1 = (const float*)d_in[2];
    const float* b1 = (const float*)d_in[3];
    const float* W2 = (const float*)d_in[4];
    const float* b2 = (const float*)d_in[5];
    float* out = (float*)d_out;

    int n = in_sizes[0];
    int ne = in_sizes[1] / 2;
    const int* row = edge_index;
    const int* col = edge_index + ne;

    int ne4 = ((ne & 3) == 0) ? (ne >> 2) : 0;
    int nodeBlocks = (n + 255) / 256;

    // ---------- path2 (R10): 2048-node 2D blocks + LDS preload ----------
    {
        int CC = (n + CN2 - 1) >> CSH2;   // col-chunks (245 @ 500K)
        int RC = CC;                       // row-chunks
        int RC1 = RC + 1;
        size_t off = 0;
        auto alloc = [&](size_t bytes) -> char* {
            char* ptr = (char*)d_ws + off;
            off += (bytes + 255) & ~(size_t)255;
            return ptr;
        };
        int* totals  = (int*)alloc((size_t)CC * sizeof(int));
        int* cbase   = (int*)alloc((size_t)(CC + 1) * sizeof(int));
        int* cursorA = (int*)alloc((size_t)CC * sizeof(int));
        int* packedA = (int*)alloc((size_t)ne * sizeof(int));
        int* packedB = (int*)alloc((size_t)ne * sizeof(int));
        int* rowh    = (int*)alloc((size_t)CC * HSL * RCB * sizeof(int));
        int* segBase = (int*)alloc((size_t)CC * RC1 * sizeof(int));
        int* cursorB = (int*)alloc((size_t)CC * RC1 * sizeof(int));
        float* dis   = (float*)alloc((size_t)n * sizeof(float));
        float* p     = (float*)alloc((size_t)n * sizeof(float));
        float* gp    = (float*)alloc((size_t)n * 2 * sizeof(float));
        // pcnt (ushort[HSL][n] = 8MB) aliases packedB (dead until k_sortB)
        unsigned short* pcnt = (unsigned short*)packedB;
        bool pcnt_fits = ((size_t)HSL * n * sizeof(unsigned short)) <= (size_t)ne * sizeof(int);
        // sPart (float[SSL][n]) + oPart (float2[SSL][n]) alias packedA (dead after sortB)
        float* sPart = (float*)packedA;
        float* oPart = (float*)(packedA + (size_t)SSL * n);
        bool part_fits = ((size_t)SSL * n * 3) <= (size_t)ne;  // 3 floats per node per slice

        bool ok = (off <= ws_size) && (n <= (1 << 19)) && (CC >= 1) && (CC <= RCB) &&
                  (CC <= KMAX) && (ne > 0) && pcnt_fits && part_fits;
        if (ok) {
            int partBlocks = (ne + PTILE - 1) / PTILE;
            k_zero<<<(CC + 255) / 256, 256, 0, stream>>>(totals, CC);
            k_count<CSH2><<<1024, 256, 0, stream>>>(col, ne, ne4, totals, CC);
            k_scan<<<1, 64, 0, stream>>>(totals, cbase, cursorA, CC);
            k_part<CSH2><<<partBlocks, PTPB, 0, stream>>>(row, col, ne, cursorA, packedA, CC);
            k_histAB<<<CC * HSL, 256, 0, stream>>>(packedA, cbase, pcnt, rowh, n);
            r_disp<<<nodeBlocks, 256, 0, stream>>>(x, pcnt, dis, p, n);
            k_scanB<<<CC, 64, 0, stream>>>(rowh, cbase, segBase, cursorB, RC, RC1);
            k_sortB<<<CC * SSL, 256, 0, stream>>>(packedA, cbase, cursorB, packedB, RC1);
            k_s2<<<CC * SSL, 256, 0, stream>>>(packedB, segBase, p, sPart, n, RC, RC1);
            r_gp8<<<nodeBlocks, 256, 0, stream>>>(sPart, p, dis, W1, b1, W2, gp, n);
            k_o2<<<CC * SSL, 256, 0, stream>>>(packedB, segBase, gp, oPart, n, RC, RC1);
            r_out8<<<nodeBlocks, 256, 0, stream>>>(oPart, gp, dis, b2, out, n);
            return;
        }
    }

    // ---------- path1 (R5 structure, proven 434us) ----------
    {
        int K = (n + 1023) >> 10;
        size_t off = 0;
        auto alloc = [&](size_t bytes) -> char* {
            char* ptr = (char*)d_ws + off;
            off += (bytes + 255) & ~(size_t)255;
            return ptr;
        };
        int* totals = (int*)alloc((size_t)K * sizeof(int));
        int* bbase  = (int*)alloc((size_t)(K + 1) * sizeof(int));
        int* cursor = (int*)alloc((size_t)K * sizeof(int));
        int* packed = (int*)alloc((size_t)ne * sizeof(int));
        float* dis  = (float*)alloc((size_t)n * sizeof(float));
        float* p    = (float*)alloc((size_t)n * sizeof(float));
        float* gp   = (float*)alloc((size_t)n * 2 * sizeof(float));
        float* partials = (float*)alloc((size_t)4 * n * 2 * sizeof(float));

        bool ok = (off <= ws_size) && (K >= 1) && (K <= KMAX) && (ne > 0);
        if (ok) {
            int partBlocks = (ne + PTILE - 1) / PTILE;
            k_zero<<<(K + 255) / 256, 256, 0, stream>>>(totals, K);
            k_count<10><<<1024, 256, 0, stream>>>(col, ne, ne4, totals, K);
            k_scan<<<1, 64, 0, stream>>>(totals, bbase, cursor, K);
            k_part<10><<<partBlocks, PTPB, 0, stream>>>(row, col, ne, cursor, packed, K);
            k_deg_split<10, 4><<<K * 4, ATPB, 0, stream>>>(packed, bbase, (int*)partials, n);
            r_dis_p<4><<<nodeBlocks, 256, 0, stream>>>(x, (const int*)partials, dis, p, n);
            k_s_split<10, 4><<<K * 4, ATPB, 0, stream>>>(packed, bbase, p, partials, n);
            r_gp<4><<<nodeBlocks, 256, 0, stream>>>(partials, p, dis, W1, b1, W2, gp, n);
            k_o_split<10, 4><<<K * 4, ATPB, 0, stream>>>(packed, bbase, gp, partials, n);
            r_out<4><<<nodeBlocks, 256, 0, stream>>>(partials, gp, dis, b2, out, n);
            return;
        }
    }

    // ---------- R1 fallback ----------
    {
        float* ws = (float*)d_ws;
        float* deg_dis = ws;
        float* pp = ws + n;
        float* ss = ws + 2 * (size_t)n;
        float* gpp = ws + 3 * (size_t)n;
        int edgeBlocks = 4096;
        f_init_deg<<<nodeBlocks, 256, 0, stream>>>(deg_dis, n);
        f_deg<<<edgeBlocks, 256, 0, stream>>>(col, deg_dis, ne);
        f_dis<<<nodeBlocks, 256, 0, stream>>>(x, deg_dis, pp, ss, n);
        f_scatter1<<<edgeBlocks, 256, 0, stream>>>(row, col, pp, ss, ne);
        f_node<<<nodeBlocks, 256, 0, stream>>>(deg_dis, ss, W1, b1, W2, gpp, out, n);
        f_scatter2<<<edgeBlocks, 256, 0, stream>>>(row, col, gpp, out, ne);
        f_final<<<nodeBlocks, 256, 0, stream>>>(deg_dis, b2, out, n);
    }
}

// Round 11
// 422.364 us; speedup vs baseline: 1.4665x; 1.4665x over previous
//
#include <hip/hip_runtime.h>

// GCN 2-layer collapsed (x is [N,1] => layer 1 is rank-1):
//   out[c] = dis[c]*(sum_{r->c} gp[r] + gp[c]) + b2,  gp[r] = (relu(W1*a[r]+b1)@W2)*dis[r]
//   a[r]   = dis[r]*(sum_{r'->r} p[r'] + p[r]),       p[r']=x[r']*dis[r'], dis=1/sqrt(deg+1)
//
// Empirical laws (R1-R10): global atomics 20G/s; scattered 4B stores ~10x write-through;
// gather+LDS-atomic passes pinned at ~91G edges/s (float2) / ~183G (scalar) regardless of
// occupancy (17-53%), caching, row-sorting, or LDS preload. R11: consolidate to the proven
// R4/R5 skeleton, SPLIT=1 with full fusion (deg->dis,p; s->MLP->gp; o->out), and 8-edge
// unrolled loops (2x int4 -> 8 gathers -> atomics) to isolate per-thread ILP as the wall.

#define KMAX  512
#define PTPB  512
#define PU    16
#define PTILE (PTPB * PU)

#define CSH   10
#define CN    1024
#define ATPB  256

// ---------- zero ----------
__global__ void k_zero(int* __restrict__ a, int m) {
    int i = blockIdx.x * blockDim.x + threadIdx.x;
    if (i < m) a[i] = 0;
}

// ---------- chunk histogram ----------
__global__ void k_count(const int* __restrict__ col, int ne, int ne4,
                        int* __restrict__ totals, int K) {
    __shared__ int cnt[KMAX];
    for (int i = threadIdx.x; i < K; i += blockDim.x) cnt[i] = 0;
    __syncthreads();
    int tid = blockIdx.x * blockDim.x + threadIdx.x;
    int stride = gridDim.x * blockDim.x;
    const int4* col4 = (const int4*)col;
    for (int e = tid; e < ne4; e += stride) {
        int4 cc = col4[e];
        atomicAdd(&cnt[cc.x >> CSH], 1);
        atomicAdd(&cnt[cc.y >> CSH], 1);
        atomicAdd(&cnt[cc.z >> CSH], 1);
        atomicAdd(&cnt[cc.w >> CSH], 1);
    }
    for (int e = (ne4 << 2) + tid; e < ne; e += stride)
        atomicAdd(&cnt[col[e] >> CSH], 1);
    __syncthreads();
    for (int i = threadIdx.x; i < K; i += blockDim.x)
        if (cnt[i]) atomicAdd(&totals[i], cnt[i]);
}

// ---------- serial scan (K<=512) ----------
__global__ void k_scan(const int* __restrict__ totals, int* __restrict__ bbase,
                       int* __restrict__ cursor, int K) {
    if (threadIdx.x == 0 && blockIdx.x == 0) {
        int run = 0;
        for (int k = 0; k < K; ++k) { bbase[k] = run; cursor[k] = run; run += totals[k]; }
        bbase[K] = run;
    }
}

// ---------- tile-local LDS counting sort partition (key = col>>CSH) ----------
__global__ __launch_bounds__(PTPB) void k_part(
    const int* __restrict__ row, const int* __restrict__ col, int ne,
    int* __restrict__ cursor, int* __restrict__ packed, int K)
{
    __shared__ int s_cnt[KMAX];
    __shared__ int s_start[KMAX + 1];
    __shared__ int s_cur[KMAX];
    __shared__ int s_gbase[KMAX];
    __shared__ int s_sorted[PTILE];

    int tb = blockIdx.x * PTILE;
    int tilecount = ne - tb;
    if (tilecount > PTILE) tilecount = PTILE;

    for (int i = threadIdx.x; i < K; i += PTPB) s_cnt[i] = 0;
    __syncthreads();

    int r[PU], c[PU];
    const int4* row4 = (const int4*)row;
    const int4* col4 = (const int4*)col;
    int tb4 = tb >> 2;
#pragma unroll
    for (int j = 0; j < PU / 4; ++j) {
        int g4 = tb4 + j * PTPB + threadIdx.x;
        int e = g4 << 2;
        if (e + 3 < ne) {
            int4 rr = row4[g4];
            int4 cc = col4[g4];
            r[4 * j + 0] = rr.x; r[4 * j + 1] = rr.y; r[4 * j + 2] = rr.z; r[4 * j + 3] = rr.w;
            c[4 * j + 0] = cc.x; c[4 * j + 1] = cc.y; c[4 * j + 2] = cc.z; c[4 * j + 3] = cc.w;
        } else {
#pragma unroll
            for (int q = 0; q < 4; ++q) {
                int e2 = e + q;
                if (e2 < ne) { r[4 * j + q] = row[e2]; c[4 * j + q] = col[e2]; }
                else { r[4 * j + q] = 0; c[4 * j + q] = -1; }
            }
        }
    }
#pragma unroll
    for (int j = 0; j < PU; ++j)
        if (c[j] >= 0) atomicAdd(&s_cnt[c[j] >> CSH], 1);
    __syncthreads();

    if (threadIdx.x == 0) {
        int run = 0;
        for (int k = 0; k < K; ++k) { s_start[k] = run; run += s_cnt[k]; }
        s_start[K] = run;
    }
    __syncthreads();
    if ((int)threadIdx.x < K) {
        int n0 = s_cnt[threadIdx.x];
        s_gbase[threadIdx.x] = n0 ? atomicAdd(&cursor[threadIdx.x], n0) : 0;
        s_cur[threadIdx.x] = s_start[threadIdx.x];
    }
    __syncthreads();

#pragma unroll
    for (int j = 0; j < PU; ++j) {
        if (c[j] >= 0) {
            int ck = c[j] >> CSH;
            int pos = atomicAdd(&s_cur[ck], 1);
            s_sorted[pos] = (r[j] << CSH) | (c[j] & (CN - 1));
        }
    }
    __syncthreads();

    for (int i = threadIdx.x; i < tilecount; i += PTPB) {
        int v = s_sorted[i];
        int lo = 0, hi = K;
        while (hi - lo > 1) {
            int mid = (lo + hi) >> 1;
            if (s_start[mid] <= i) lo = mid; else hi = mid;
        }
        packed[s_gbase[lo] + (i - s_start[lo])] = v;
    }
}

// ---------- fused degree -> dis, p (one block per chunk) ----------
__global__ __launch_bounds__(ATPB) void k_deg1(
    const float* __restrict__ x, const int* __restrict__ packed,
    const int* __restrict__ bbase, float* __restrict__ dis, float* __restrict__ p, int n)
{
    __shared__ int cnt[CN];
    int k = blockIdx.x;
    int node0 = k << CSH;
    int nn = min(CN, n - node0);
    for (int i = threadIdx.x; i < CN; i += ATPB) cnt[i] = 0;
    __syncthreads();
    int e0 = bbase[k], e1 = bbase[k + 1];
    int a0 = min((e0 + 3) & ~3, e1);
    int nb = (e1 - a0) >> 3;   // 8-edge groups
    for (int e = e0 + (int)threadIdx.x; e < a0; e += ATPB)
        atomicAdd(&cnt[packed[e] & (CN - 1)], 1);
    const int4* pk4 = (const int4*)packed;
    int b4 = a0 >> 2;
    for (int g = threadIdx.x; g < nb; g += ATPB) {
        int4 v0 = pk4[b4 + 2 * g];
        int4 v1 = pk4[b4 + 2 * g + 1];
        atomicAdd(&cnt[v0.x & (CN - 1)], 1);
        atomicAdd(&cnt[v0.y & (CN - 1)], 1);
        atomicAdd(&cnt[v0.z & (CN - 1)], 1);
        atomicAdd(&cnt[v0.w & (CN - 1)], 1);
        atomicAdd(&cnt[v1.x & (CN - 1)], 1);
        atomicAdd(&cnt[v1.y & (CN - 1)], 1);
        atomicAdd(&cnt[v1.z & (CN - 1)], 1);
        atomicAdd(&cnt[v1.w & (CN - 1)], 1);
    }
    for (int e = a0 + 8 * nb + (int)threadIdx.x; e < e1; e += ATPB)
        atomicAdd(&cnt[packed[e] & (CN - 1)], 1);
    __syncthreads();
    for (int i = threadIdx.x; i < nn; i += ATPB) {
        float ds = rsqrtf(1.0f + (float)cnt[i]);
        dis[node0 + i] = ds;
        p[node0 + i] = x[node0 + i] * ds;
    }
}

// ---------- fused scalar aggregation + MLP -> gp (one block per chunk) ----------
__global__ __launch_bounds__(ATPB) void k_s1(
    const int* __restrict__ packed, const int* __restrict__ bbase,
    const float* __restrict__ p, const float* __restrict__ dis,
    const float* __restrict__ W1, const float* __restrict__ b1,
    const float* __restrict__ W2, float* __restrict__ gp, int n)
{
    __shared__ float sv[CN];
    int k = blockIdx.x;
    int node0 = k << CSH;
    int nn = min(CN, n - node0);
    for (int i = threadIdx.x; i < CN; i += ATPB) sv[i] = 0.0f;
    __syncthreads();
    int e0 = bbase[k], e1 = bbase[k + 1];
    int a0 = min((e0 + 3) & ~3, e1);
    int nb = (e1 - a0) >> 3;
    for (int e = e0 + (int)threadIdx.x; e < a0; e += ATPB) {
        int v = packed[e];
        atomicAdd(&sv[v & (CN - 1)], p[((unsigned)v) >> CSH]);
    }
    const int4* pk4 = (const int4*)packed;
    int b4 = a0 >> 2;
    for (int g = threadIdx.x; g < nb; g += ATPB) {
        int4 v0 = pk4[b4 + 2 * g];
        int4 v1 = pk4[b4 + 2 * g + 1];
        float p0 = p[((unsigned)v0.x) >> CSH];
        float p1 = p[((unsigned)v0.y) >> CSH];
        float p2 = p[((unsigned)v0.z) >> CSH];
        float p3 = p[((unsigned)v0.w) >> CSH];
        float p4 = p[((unsigned)v1.x) >> CSH];
        float p5 = p[((unsigned)v1.y) >> CSH];
        float p6 = p[((unsigned)v1.z) >> CSH];
        float p7 = p[((unsigned)v1.w) >> CSH];
        atomicAdd(&sv[v0.x & (CN - 1)], p0);
        atomicAdd(&sv[v0.y & (CN - 1)], p1);
        atomicAdd(&sv[v0.z & (CN - 1)], p2);
        atomicAdd(&sv[v0.w & (CN - 1)], p3);
        atomicAdd(&sv[v1.x & (CN - 1)], p4);
        atomicAdd(&sv[v1.y & (CN - 1)], p5);
        atomicAdd(&sv[v1.z & (CN - 1)], p6);
        atomicAdd(&sv[v1.w & (CN - 1)], p7);
    }
    for (int e = a0 + 8 * nb + (int)threadIdx.x; e < e1; e += ATPB) {
        int v = packed[e];
        atomicAdd(&sv[v & (CN - 1)], p[((unsigned)v) >> CSH]);
    }
    __syncthreads();
    float2* gp2 = (float2*)gp;
    for (int i = threadIdx.x; i < nn; i += ATPB) {
        int node = node0 + i;
        float d = dis[node];
        float a = d * (sv[i] + p[node]);   // + self-loop
        float g0 = 0.0f, g1 = 0.0f;
#pragma unroll
        for (int q = 0; q < 16; ++q) {
            float h = fmaxf(W1[q] * a + b1[q], 0.0f);
            g0 += h * W2[2 * q];
            g1 += h * W2[2 * q + 1];
        }
        gp2[node] = make_float2(g0 * d, g1 * d);
    }
}

// ---------- fused float2 aggregation + bias -> out (one block per chunk) ----------
__global__ __launch_bounds__(ATPB) void k_o1(
    const int* __restrict__ packed, const int* __restrict__ bbase,
    const float* __restrict__ gp, const float* __restrict__ dis,
    const float* __restrict__ b2, float* __restrict__ out, int n)
{
    __shared__ float ox[CN];
    __shared__ float oy[CN];
    int k = blockIdx.x;
    int node0 = k << CSH;
    int nn = min(CN, n - node0);
    for (int i = threadIdx.x; i < CN; i += ATPB) { ox[i] = 0.0f; oy[i] = 0.0f; }
    __syncthreads();
    int e0 = bbase[k], e1 = bbase[k + 1];
    int a0 = min((e0 + 3) & ~3, e1);
    int nb = (e1 - a0) >> 3;
    const float2* gp2 = (const float2*)gp;
    for (int e = e0 + (int)threadIdx.x; e < a0; e += ATPB) {
        int v = packed[e];
        float2 g = gp2[((unsigned)v) >> CSH];
        atomicAdd(&ox[v & (CN - 1)], g.x);
        atomicAdd(&oy[v & (CN - 1)], g.y);
    }
    const int4* pk4 = (const int4*)packed;
    int b4 = a0 >> 2;
    for (int g = threadIdx.x; g < nb; g += ATPB) {
        int4 v0 = pk4[b4 + 2 * g];
        int4 v1 = pk4[b4 + 2 * g + 1];
        float2 g0 = gp2[((unsigned)v0.x) >> CSH];
        float2 g1 = gp2[((unsigned)v0.y) >> CSH];
        float2 g2 = gp2[((unsigned)v0.z) >> CSH];
        float2 g3 = gp2[((unsigned)v0.w) >> CSH];
        float2 g4 = gp2[((unsigned)v1.x) >> CSH];
        float2 g5 = gp2[((unsigned)v1.y) >> CSH];
        float2 g6 = gp2[((unsigned)v1.z) >> CSH];
        float2 g7 = gp2[((unsigned)v1.w) >> CSH];
        atomicAdd(&ox[v0.x & (CN - 1)], g0.x);
        atomicAdd(&oy[v0.x & (CN - 1)], g0.y);
        atomicAdd(&ox[v0.y & (CN - 1)], g1.x);
        atomicAdd(&oy[v0.y & (CN - 1)], g1.y);
        atomicAdd(&ox[v0.z & (CN - 1)], g2.x);
        atomicAdd(&oy[v0.z & (CN - 1)], g2.y);
        atomicAdd(&ox[v0.w & (CN - 1)], g3.x);
        atomicAdd(&oy[v0.w & (CN - 1)], g3.y);
        atomicAdd(&ox[v1.x & (CN - 1)], g4.x);
        atomicAdd(&oy[v1.x & (CN - 1)], g4.y);
        atomicAdd(&ox[v1.y & (CN - 1)], g5.x);
        atomicAdd(&oy[v1.y & (CN - 1)], g5.y);
        atomicAdd(&ox[v1.z & (CN - 1)], g6.x);
        atomicAdd(&oy[v1.z & (CN - 1)], g6.y);
        atomicAdd(&ox[v1.w & (CN - 1)], g7.x);
        atomicAdd(&oy[v1.w & (CN - 1)], g7.y);
    }
    for (int e = a0 + 8 * nb + (int)threadIdx.x; e < e1; e += ATPB) {
        int v = packed[e];
        float2 g = gp2[((unsigned)v) >> CSH];
        atomicAdd(&ox[v & (CN - 1)], g.x);
        atomicAdd(&oy[v & (CN - 1)], g.y);
    }
    __syncthreads();
    float b20 = b2[0], b21 = b2[1];
    float2* out2 = (float2*)out;
    for (int i = threadIdx.x; i < nn; i += ATPB) {
        int node = node0 + i;
        float d = dis[node];
        float2 g = gp2[node];
        out2[node] = make_float2(d * (ox[i] + g.x) + b20, d * (oy[i] + g.y) + b21);
    }
}

// ---------- R1 fallback ----------
__global__ void f_init_deg(float* __restrict__ deg, int n) {
    int i = blockIdx.x * blockDim.x + threadIdx.x;
    if (i < n) deg[i] = 1.0f;
}
__global__ void f_deg(const int* __restrict__ col, float* __restrict__ deg, int ne) {
    int tid = blockIdx.x * blockDim.x + threadIdx.x;
    int stride = gridDim.x * blockDim.x;
    for (int e = tid; e < ne; e += stride) atomicAdd(&deg[col[e]], 1.0f);
}
__global__ void f_dis(const float* __restrict__ x, float* __restrict__ deg_dis,
                      float* __restrict__ p, float* __restrict__ s, int n) {
    int i = blockIdx.x * blockDim.x + threadIdx.x;
    if (i >= n) return;
    float dis = rsqrtf(deg_dis[i]);
    deg_dis[i] = dis;
    float pv = x[i] * dis;
    p[i] = pv;
    s[i] = pv;
}
__global__ void f_scatter1(const int* __restrict__ row, const int* __restrict__ col,
                           const float* __restrict__ p, float* __restrict__ s, int ne) {
    int tid = blockIdx.x * blockDim.x + threadIdx.x;
    int stride = gridDim.x * blockDim.x;
    for (int e = tid; e < ne; e += stride) atomicAdd(&s[col[e]], p[row[e]]);
}
__global__ void f_node(const float* __restrict__ dis, const float* __restrict__ s,
                       const float* __restrict__ W1, const float* __restrict__ b1,
                       const float* __restrict__ W2,
                       float* __restrict__ gp, float* __restrict__ out, int n) {
    int i = blockIdx.x * blockDim.x + threadIdx.x;
    if (i >= n) return;
    float d = dis[i];
    float a = d * s[i];
    float g0 = 0.0f, g1 = 0.0f;
#pragma unroll
    for (int q = 0; q < 16; ++q) {
        float h = fmaxf(W1[q] * a + b1[q], 0.0f);
        g0 += h * W2[2 * q];
        g1 += h * W2[2 * q + 1];
    }
    ((float2*)gp)[i] = make_float2(g0 * d, g1 * d);
    ((float2*)out)[i] = make_float2(g0 * d, g1 * d);
}
__global__ void f_scatter2(const int* __restrict__ row, const int* __restrict__ col,
                           const float* __restrict__ gp, float* __restrict__ out, int ne) {
    int tid = blockIdx.x * blockDim.x + threadIdx.x;
    int stride = gridDim.x * blockDim.x;
    const float2* gp2 = (const float2*)gp;
    for (int e = tid; e < ne; e += stride) {
        float2 g = gp2[row[e]];
        atomicAdd(&out[2 * col[e]], g.x);
        atomicAdd(&out[2 * col[e] + 1], g.y);
    }
}
__global__ void f_final(const float* __restrict__ dis, const float* __restrict__ b2,
                        float* __restrict__ out, int n) {
    int i = blockIdx.x * blockDim.x + threadIdx.x;
    if (i >= n) return;
    float d = dis[i];
    float2* out2 = (float2*)out;
    float2 t = out2[i];
    out2[i] = make_float2(d * t.x + b2[0], d * t.y + b2[1]);
}

// ---------------- launch ----------------

extern "C" void kernel_launch(void* const* d_in, const int* in_sizes, int n_in,
                              void* d_out, int out_size, void* d_ws, size_t ws_size,
                              hipStream_t stream) {
    const float* x = (const float*)d_in[0];
    const int* edge_index = (const int*)d_in[1];
    const float* W1 = (const float*)d_in[2];
    const float* b1 = (const float*)d_in[3];
    const float* W2 = (const float*)d_in[4];
    const float* b2 = (const float*)d_in[5];
    float* out = (float*)d_out;

    int n = in_sizes[0];
    int ne = in_sizes[1] / 2;
    const int* row = edge_index;
    const int* col = edge_index + ne;

    int ne4 = ((ne & 3) == 0) ? (ne >> 2) : 0;
    int nodeBlocks = (n + 255) / 256;

    // ---------- main path: R4/R5 skeleton, fully fused, 8-edge ILP loops ----------
    {
        int K = (n + CN - 1) >> CSH;
        size_t off = 0;
        auto alloc = [&](size_t bytes) -> char* {
            char* ptr = (char*)d_ws + off;
            off += (bytes + 255) & ~(size_t)255;
            return ptr;
        };
        int* totals = (int*)alloc((size_t)K * sizeof(int));
        int* bbase  = (int*)alloc((size_t)(K + 1) * sizeof(int));
        int* cursor = (int*)alloc((size_t)K * sizeof(int));
        int* packed = (int*)alloc((size_t)ne * sizeof(int));
        float* dis  = (float*)alloc((size_t)n * sizeof(float));
        float* p    = (float*)alloc((size_t)n * sizeof(float));
        float* gp   = (float*)alloc((size_t)n * 2 * sizeof(float));

        bool ok = (off <= ws_size) && (K >= 1) && (K <= KMAX) && (ne > 0);
        if (ok) {
            int partBlocks = (ne + PTILE - 1) / PTILE;
            k_zero<<<(K + 255) / 256, 256, 0, stream>>>(totals, K);
            k_count<<<1024, 256, 0, stream>>>(col, ne, ne4, totals, K);
            k_scan<<<1, 64, 0, stream>>>(totals, bbase, cursor, K);
            k_part<<<partBlocks, PTPB, 0, stream>>>(row, col, ne, cursor, packed, K);
            k_deg1<<<K, ATPB, 0, stream>>>(x, packed, bbase, dis, p, n);
            k_s1<<<K, ATPB, 0, stream>>>(packed, bbase, p, dis, W1, b1, W2, gp, n);
            k_o1<<<K, ATPB, 0, stream>>>(packed, bbase, gp, dis, b2, out, n);
            return;
        }
    }

    // ---------- R1 fallback ----------
    {
        float* ws = (float*)d_ws;
        float* deg_dis = ws;
        float* pp = ws + n;
        float* ss = ws + 2 * (size_t)n;
        float* gpp = ws + 3 * (size_t)n;
        int edgeBlocks = 4096;
        f_init_deg<<<nodeBlocks, 256, 0, stream>>>(deg_dis, n);
        f_deg<<<edgeBlocks, 256, 0, stream>>>(col, deg_dis, ne);
        f_dis<<<nodeBlocks, 256, 0, stream>>>(x, deg_dis, pp, ss, n);
        f_scatter1<<<edgeBlocks, 256, 0, stream>>>(row, col, pp, ss, ne);
        f_node<<<nodeBlocks, 256, 0, stream>>>(deg_dis, ss, W1, b1, W2, gpp, out, n);
        f_scatter2<<<edgeBlocks, 256, 0, stream>>>(row, col, gpp, out, ne);
        f_final<<<nodeBlocks, 256, 0, stream>>>(deg_dis, b2, out, n);
    }
}